// Round 20
// baseline (326.899 us; speedup 1.0000x reference)
//
#include <hip/hip_runtime.h>

typedef short short8 __attribute__((ext_vector_type(8)));
typedef short short4v __attribute__((ext_vector_type(4)));
typedef float f32x4 __attribute__((ext_vector_type(4)));
typedef unsigned int u32;

#define EPSF 1e-5f
#define THRF 0.2987f

constexpr int N_ = 64, C_ = 128;
constexpr int PLANE = 4096;
constexpr size_t TENSOR = (size_t)N_ * C_ * PLANE;  // 33554432
constexpr int NHW = N_ * PLANE;                     // 262144
constexpr int PUNITS = 66 * 66 * 8;                 // 34848 16B-units per (half,n) plane

__device__ __forceinline__ unsigned short f2bf(float f) {
    unsigned u = __float_as_uint(f);
    u += 0x7fffu + ((u >> 16) & 1u);  // RNE
    return (unsigned short)(u >> 16);
}
__device__ __forceinline__ float bf2f(unsigned short h) {
    return __uint_as_float((unsigned)h << 16);
}
__device__ __forceinline__ void gld16(const unsigned short* g, unsigned short* l) {
    __builtin_amdgcn_global_load_lds(
        (const __attribute__((address_space(1))) u32*)g,
        (__attribute__((address_space(3))) u32*)l, 16, 0, 0);
}

// ---------- weight prep: [co][ci][3][3] fp32 -> [36 steps][128 co][32 ci] bf16
__global__ __launch_bounds__(256) void prep_w_k(const float* __restrict__ w1,
                                                const float* __restrict__ w2,
                                                unsigned short* __restrict__ Wt1,
                                                unsigned short* __restrict__ Wt2) {
    int idx = blockIdx.x * 256 + threadIdx.x;  // 0..294911
    const int sel = idx >= 147456;
    const float* src = sel ? w2 : w1;
    unsigned short* dst = sel ? Wt2 : Wt1;
    const int r = idx - sel * 147456;
    const int tap = r >> 14;
    const int rem = r & 16383;
    const int co = rem >> 7, ci = rem & 127;
    const int half = ci >> 6, csh = (ci >> 5) & 1;
    const int s = half * 18 + tap * 2 + csh;
    dst[(size_t)s * 4096 + co * 32 + (ci & 31)] = f2bf(src[(co * 128 + ci) * 9 + tap]);
}

// ---------- NCHW fp32 -> padded swizzled NHWC bf16 (interior) + border zeroing (tail blocks)
__global__ __launch_bounds__(256) void to_nhwc_k(const float* __restrict__ src,
                                                 unsigned short* __restrict__ dst) {
    const int b = blockIdx.x;
    if (b >= 16384) {
        // border zeroing: blocks 16384..17423 cover 128 planes x 2080 units
        int idx = (b - 16384) * 256 + threadIdx.x;
        if (idx < 266240) {
            const int plane = idx / 2080;
            const int t = idx - plane * 2080;
            int sp;
            if (t < 528) sp = t >> 3;
            else if (t < 1056) sp = 65 * 66 + ((t - 528) >> 3);
            else if (t < 1568) sp = (((t - 1056) >> 3) + 1) * 66;
            else sp = (((t - 1568) >> 3) + 1) * 66 + 65;
            const size_t off = ((size_t)plane * PUNITS + sp * 8 + (t & 7)) * 8;
            *(short8*)&dst[off] = (short8){0, 0, 0, 0, 0, 0, 0, 0};
        }
        return;
    }
    __shared__ __align__(16) unsigned short tl[64 * 40];
    const int c0 = (b & 3) * 32;
    const int h  = (b >> 2) & 63;
    const int n  = b >> 8;
    const int t  = threadIdx.x;
    for (int i = t; i < 512; i += 256) {
        const int cl = i >> 4;
        const int c  = c0 + cl;
        const int w4 = (i & 15) * 4;
        float4 v = *(const float4*)&src[(size_t)(n * 128 + c) * 4096 + h * 64 + w4];
        tl[(w4 + 0) * 40 + cl] = f2bf(v.x);
        tl[(w4 + 1) * 40 + cl] = f2bf(v.y);
        tl[(w4 + 2) * 40 + cl] = f2bf(v.z);
        tl[(w4 + 3) * 40 + cl] = f2bf(v.w);
    }
    __syncthreads();
    const int w = t >> 2, cs = t & 3;
    short8 v = *(const short8*)&tl[w * 40 + cs * 8];
    const int c = c0 + cs * 8;
    const int half = c >> 6, cig = (c >> 3) & 7;
    const int colp = w + 1, rowp = h + 1;
    const size_t off = ((size_t)(half * 64 + n) * PUNITS
                        + (size_t)(rowp * 66 + colp) * 8 + (cig ^ (colp & 7))) * 8;
    *(short8*)&dst[off] = v;
}

// ---------- conv3x3 MFMA implicit GEMM (R17 core + 4-deep weight register ring) ----------
template <int STAGE>
__global__ __launch_bounds__(256, 3) void conv_mfma_k(
    const unsigned short* __restrict__ inT, const unsigned short* __restrict__ Wt,
    const float* __restrict__ msA, const float* __restrict__ mhA,
    unsigned short* __restrict__ outB, float* __restrict__ part) {
    __shared__ __align__(16) unsigned short sIn[2112 * 8];  // 33,792 B
    __shared__ float fS[256], fQ[256];                      // 2,048 B

    // XCD-chunked bijective swizzle (2048 % 8 == 0)
    const int b  = (blockIdx.x & 7) * 256 + (blockIdx.x >> 3);
    const int h0 = (b & 31) * 2;
    const int n  = b >> 5;
    const int tid  = threadIdx.x;
    const int lane = tid & 63;
    const int wid  = tid >> 6;
    const int co_base = (wid >> 1) * 64;
    const int px_base = (wid & 1) * 64;
    const int lr = lane & 15;
    const int lg = lane >> 4;

    f32x4 acc[4][4];
#pragma unroll
    for (int i = 0; i < 4; ++i)
#pragma unroll
        for (int j = 0; j < 4; ++j) acc[i][j] = (f32x4){0.f, 0.f, 0.f, 0.f};

    const int nc = n * 128;
    const unsigned short* wlane = Wt + (size_t)(co_base + lr) * 32 + lg * 8;

    // Precomputed per-lane LDS byte addresses
    int ldsQ[4][2][3];
#pragma unroll
    for (int j = 0; j < 4; ++j) {
        const int px = px_base + j * 16 + lr;
        const int r = px >> 6, c = px & 63;
#pragma unroll
        for (int csh = 0; csh < 2; ++csh)
#pragma unroll
            for (int dc = 0; dc < 3; ++dc) {
                const int cig = csh * 4 + lg;
                ldsQ[j][csh][dc] = (r * 66 + c + dc) * 128 + (cig ^ ((c + dc) & 7)) * 16;
            }
    }

    auto stage_in = [&](int half) {
        const unsigned short* src =
            inT + ((size_t)(half * 64 + n) * PUNITS + (size_t)h0 * 66 * 8) * 8;
        if (STAGE == 1) {
            for (int c = wid; c < 33; c += 4)
                gld16(src + (c * 64 + lane) * 8, &sIn[c * 512]);
        } else {
            const int ncb = nc + half * 64;
            for (int i = tid; i < 2112; i += 256) {
                const int sp = i >> 3, ul = i & 7;
                const int rq = sp / 66;
                const int colp = sp - rq * 66;
                const int rp = h0 + rq;
                short8 v = {0, 0, 0, 0, 0, 0, 0, 0};
                if (rp != 0 && rp != 65 && colp != 0 && colp != 65) {
                    v = *(const short8*)&src[i * 8];
                    const int cig = ul ^ (colp & 7);
                    const int cb = ncb + cig * 8;
                    const float4 m0 = *(const float4*)&msA[cb];
                    const float4 m1 = *(const float4*)&msA[cb + 4];
                    const float4 a0 = *(const float4*)&mhA[cb];
                    const float4 a1 = *(const float4*)&mhA[cb + 4];
                    short8 w;
                    w[0] = (short)f2bf(fmaxf(fmaf(bf2f((unsigned short)v[0]), m0.x, a0.x), 0.f));
                    w[1] = (short)f2bf(fmaxf(fmaf(bf2f((unsigned short)v[1]), m0.y, a0.y), 0.f));
                    w[2] = (short)f2bf(fmaxf(fmaf(bf2f((unsigned short)v[2]), m0.z, a0.z), 0.f));
                    w[3] = (short)f2bf(fmaxf(fmaf(bf2f((unsigned short)v[3]), m0.w, a0.w), 0.f));
                    w[4] = (short)f2bf(fmaxf(fmaf(bf2f((unsigned short)v[4]), m1.x, a1.x), 0.f));
                    w[5] = (short)f2bf(fmaxf(fmaf(bf2f((unsigned short)v[5]), m1.y, a1.y), 0.f));
                    w[6] = (short)f2bf(fmaxf(fmaf(bf2f((unsigned short)v[6]), m1.z, a1.z), 0.f));
                    w[7] = (short)f2bf(fmaxf(fmaf(bf2f((unsigned short)v[7]), m1.w, a1.w), 0.f));
                    v = w;
                }
                *(short8*)&sIn[i * 8] = v;
            }
        }
    };

    auto ldw2 = [&](short8* dst, const unsigned short* p) {
#pragma unroll
        for (int i = 0; i < 4; ++i)
            dst[i] = *(const short8*)&p[i * 512];
    };
    auto ldb = [&](short8* bfv, int dr, int dc, int csh) {
#pragma unroll
        for (int j = 0; j < 4; ++j)
            bfv[j] = *(const short8*)((const char*)sIn + ldsQ[j][csh][dc] + dr * 8448);
    };
    auto mm = [&](short8* af, short8* bfv) {
        __builtin_amdgcn_s_setprio(1);
#pragma unroll
        for (int i = 0; i < 4; ++i)
#pragma unroll
            for (int j = 0; j < 4; ++j)
                acc[i][j] = __builtin_amdgcn_mfma_f32_16x16x32_bf16(af[i], bfv[j],
                                                                    acc[i][j], 0, 0, 0);
        __builtin_amdgcn_s_setprio(0);
    };

    // 4-deep weight register ring: slot = it&1 holds slices (2it, 2it+1);
    // reload slices (2it+4, 2it+5) -> 2-iteration (~640 cyc) lead covers L2 latency.
    short8 afA0[4], afB0[4], afA1[4], afB1[4], bfv[4];

    // ---- prologue
    stage_in(0);
    ldw2(afA0, wlane);                       // slice 0
    ldw2(afB0, wlane + (size_t)1 * 4096);    // slice 1
    ldw2(afA1, wlane + (size_t)2 * 4096);    // slice 2
    ldw2(afB1, wlane + (size_t)3 * 4096);    // slice 3
    __syncthreads();

#pragma unroll
    for (int it = 0; it < 18; ++it) {
        const int tap = it % 9;
        const int dr = tap / 3, dc = tap - dr * 3;
        if (it == 9) {
            __syncthreads();  // all waves done reading sIn half0
            stage_in(1);
            __syncthreads();  // sIn half1 visible
        }
        if ((it & 1) == 0) {
            ldb(bfv, dr, dc, 0);
            mm(afA0, bfv);
            if (2 * it + 4 < 36) ldw2(afA0, wlane + (size_t)(2 * it + 4) * 4096);
            ldb(bfv, dr, dc, 1);
            mm(afB0, bfv);
            if (2 * it + 5 < 36) ldw2(afB0, wlane + (size_t)(2 * it + 5) * 4096);
        } else {
            ldb(bfv, dr, dc, 0);
            mm(afA1, bfv);
            if (2 * it + 4 < 36) ldw2(afA1, wlane + (size_t)(2 * it + 4) * 4096);
            ldb(bfv, dr, dc, 1);
            mm(afB1, bfv);
            if (2 * it + 5 < 36) ldw2(afB1, wlane + (size_t)(2 * it + 5) * 4096);
        }
    }

    // ---- BN partials
#pragma unroll
    for (int i = 0; i < 4; ++i)
#pragma unroll
        for (int q = 0; q < 4; ++q) {
            float v = acc[i][0][q] + acc[i][1][q] + acc[i][2][q] + acc[i][3][q];
            float w = acc[i][0][q] * acc[i][0][q] + acc[i][1][q] * acc[i][1][q]
                    + acc[i][2][q] * acc[i][2][q] + acc[i][3][q] * acc[i][3][q];
#pragma unroll
            for (int m = 1; m < 16; m <<= 1) {
                v += __shfl_xor(v, m);
                w += __shfl_xor(w, m);
            }
            if (lr == 0) {
                const int colocal = i * 16 + lg * 4 + q;
                fS[wid * 64 + colocal] = v;
                fQ[wid * 64 + colocal] = w;
            }
        }
    __syncthreads();
    if (tid < 128) {
        const int grp = tid >> 6, cl = tid & 63;
        part[(size_t)b * 256 + tid]       = fS[(grp * 2) * 64 + cl] + fS[(grp * 2 + 1) * 64 + cl];
        part[(size_t)b * 256 + 128 + tid] = fQ[(grp * 2) * 64 + cl] + fQ[(grp * 2 + 1) * 64 + cl];
    }

    // ---- write output
    if (STAGE == 1) {
        const int h = h0 + (px_base >> 6);
        const int rowp = h + 1;
        const size_t plane = (size_t)((co_base >> 6) * 64 + n) * PUNITS * 8;
        const int pg = lg >> 1;
#pragma unroll
        for (int j = 0; j < 4; ++j) {
            const int w = j * 16 + lr;
            const int colp = w + 1;
            const size_t spoff = plane + (size_t)(rowp * 66 + colp) * 8 * 8;
#pragma unroll
            for (int i = 0; i < 4; ++i) {
                u32 p0 = ((u32)f2bf(acc[i][j][1]) << 16) | f2bf(acc[i][j][0]);
                u32 p1 = ((u32)f2bf(acc[i][j][3]) << 16) | f2bf(acc[i][j][2]);
                const u32 q0 = __shfl_xor(p0, 16);
                const u32 q1 = __shfl_xor(p1, 16);
                if ((lg & 1) == 0) {
                    const int cig = (i * 2 + pg) & 7;
                    u32 st4[4] = {p0, p1, q0, q1};
                    *(short8*)&outB[spoff + (size_t)(cig ^ (colp & 7)) * 8] =
                        *(const short8*)st4;
                }
            }
        }
    } else {
        const size_t outN = (size_t)n * 128 * 4096;
#pragma unroll
        for (int i = 0; i < 4; ++i) {
            const int cob = co_base + i * 16 + lg * 4;
#pragma unroll
            for (int q = 0; q < 4; ++q) {
                unsigned short* op = outB + outN + (size_t)(cob + q) * 4096
                                     + h0 * 64 + px_base + lr;
#pragma unroll
                for (int j = 0; j < 4; ++j) op[j * 16] = f2bf(acc[i][j][q]);
            }
        }
    }
}

// ---------- fold per-block partials -> per-channel scale/shift ----------
__global__ __launch_bounds__(256) void bn_finalize_k(const float* __restrict__ part,
                                                     const float* __restrict__ gamma,
                                                     const float* __restrict__ beta,
                                                     float* __restrict__ st) {
    const int c = blockIdx.x;
    float s = 0.f, q = 0.f;
    for (int b = threadIdx.x; b < 2048; b += 256) {
        s += part[(size_t)b * 256 + c];
        q += part[(size_t)b * 256 + 128 + c];
    }
    __shared__ float rs[256], rq[256];
    rs[threadIdx.x] = s; rq[threadIdx.x] = q;
    __syncthreads();
    for (int o = 128; o > 0; o >>= 1) {
        if (threadIdx.x < o) {
            rs[threadIdx.x] += rs[threadIdx.x + o];
            rq[threadIdx.x] += rq[threadIdx.x + o];
        }
        __syncthreads();
    }
    if (threadIdx.x == 0) {
        const float inv  = 1.f / (float)NHW;
        const float mean = rs[0] * inv;
        const float var  = rq[0] * inv - mean * mean;
        const float sc   = gamma[c] * rsqrtf(var + EPSF);
        st[c]       = sc;
        st[C_ + c]  = fmaf(-mean, sc, beta[c]);
    }
}

// ---------- per-(n,half,row-quarter) partial sums of relu(bn1(y1)) ----------
__global__ __launch_bounds__(256) void maskpart_k(const unsigned short* __restrict__ y1,
                                                  const float* __restrict__ st,
                                                  float* __restrict__ qsum) {
    const int blk = blockIdx.x;
    const int n = blk >> 3, half = (blk >> 2) & 1, rq = blk & 3;
    const int t = threadIdx.x;
    const int colg = t & 63;
    const int p = t >> 6;
    const int colp = 1 + colg;
    float scv[2][8], shv[2][8], a[2][8];
#pragma unroll
    for (int k = 0; k < 2; ++k)
#pragma unroll
        for (int e = 0; e < 8; ++e) {
            const int c = half * 64 + (2 * p + k) * 8 + e;
            scv[k][e] = st[c];
            shv[k][e] = st[128 + c];
            a[k][e] = 0.f;
        }
    const size_t plane = (size_t)(half * 64 + n) * PUNITS * 8;
    for (int rowp = rq * 16 + 1; rowp <= rq * 16 + 16; ++rowp) {
        const int sp = rowp * 66 + colp;
#pragma unroll
        for (int k = 0; k < 2; ++k) {
            const int cig = 2 * p + k;
            short8 v = *(const short8*)&y1[plane + ((size_t)sp * 8 + (cig ^ (colp & 7))) * 8];
#pragma unroll
            for (int e = 0; e < 8; ++e)
                a[k][e] += fmaxf(fmaf(bf2f((unsigned short)v[e]), scv[k][e], shv[k][e]), 0.f);
        }
    }
    __shared__ float lds[256][16];
#pragma unroll
    for (int k = 0; k < 2; ++k)
#pragma unroll
        for (int e = 0; e < 8; ++e) lds[t][k * 8 + e] = a[k][e];
    __syncthreads();
    if (t < 64) {
        const int cig = t >> 3, e = t & 7, p2 = cig >> 1, k2 = cig & 1;
        float s = 0.f;
        for (int cg = 0; cg < 64; ++cg) s += lds[p2 * 64 + cg][k2 * 8 + e];
        qsum[(size_t)blk * 64 + t] = s;
    }
}

// ---------- finalize mask -> combined ms/mh per (n,c) ----------
__global__ void maskfin_k(const float* __restrict__ qsum, const float* __restrict__ st,
                          float* __restrict__ msA, float* __restrict__ mhA) {
    const int n = blockIdx.x, c = threadIdx.x;
    if (c >= 128) return;
    const int half = c >> 6, cl = c & 63;
    float s = 0.f;
#pragma unroll
    for (int rq = 0; rq < 4; ++rq)
        s += qsum[(size_t)(n * 8 + half * 4 + rq) * 64 + cl];
    const float m = (s * (1.f / 4096.f) >= THRF) ? 1.f : 0.f;
    msA[n * 128 + c] = st[c] * m;
    mhA[n * 128 + c] = st[128 + c] * m;
}

// ---------- final: relu(bn2(y3 bf16) + x), NCHW fp32 out ----------
__global__ __launch_bounds__(256) void final_k(const unsigned short* __restrict__ y3,
                                               const float* __restrict__ x,
                                               const float* __restrict__ st,
                                               float* __restrict__ out) {
    const size_t total8 = TENSOR / 8;
    for (size_t g = (size_t)blockIdx.x * 256 + threadIdx.x; g < total8;
         g += (size_t)gridDim.x * 256) {
        const int c = (int)((g >> 9) & (C_ - 1));
        const float sc = st[c], sh = st[C_ + c];
        short8 yv = *(const short8*)&y3[g * 8];
        float4 a0 = ((const float4*)x)[g * 2];
        float4 a1 = ((const float4*)x)[g * 2 + 1];
        float4 o0, o1;
        o0.x = fmaxf(fmaf(bf2f((unsigned short)yv[0]), sc, sh) + a0.x, 0.f);
        o0.y = fmaxf(fmaf(bf2f((unsigned short)yv[1]), sc, sh) + a0.y, 0.f);
        o0.z = fmaxf(fmaf(bf2f((unsigned short)yv[2]), sc, sh) + a0.z, 0.f);
        o0.w = fmaxf(fmaf(bf2f((unsigned short)yv[3]), sc, sh) + a0.w, 0.f);
        o1.x = fmaxf(fmaf(bf2f((unsigned short)yv[4]), sc, sh) + a1.x, 0.f);
        o1.y = fmaxf(fmaf(bf2f((unsigned short)yv[5]), sc, sh) + a1.y, 0.f);
        o1.z = fmaxf(fmaf(bf2f((unsigned short)yv[6]), sc, sh) + a1.z, 0.f);
        o1.w = fmaxf(fmaf(bf2f((unsigned short)yv[7]), sc, sh) + a1.w, 0.f);
        ((float4*)out)[g * 2]     = o0;
        ((float4*)out)[g * 2 + 1] = o1;
    }
}

extern "C" void kernel_launch(void* const* d_in, const int* in_sizes, int n_in,
                              void* d_out, int out_size, void* d_ws, size_t ws_size,
                              hipStream_t stream) {
    const float* x  = (const float*)d_in[0];
    const float* w1 = (const float*)d_in[1];
    const float* g1 = (const float*)d_in[2];
    const float* b1 = (const float*)d_in[3];
    const float* w2 = (const float*)d_in[4];
    const float* g2 = (const float*)d_in[5];
    const float* b2 = (const float*)d_in[6];
    float* out = (float*)d_out;

    // y1 (padded swizzled bf16, 71.4MB) lives in d_out; final overwrites it.
    unsigned short* y1 = (unsigned short*)d_out;

    char* wsb = (char*)d_ws;
    unsigned short* io  = (unsigned short*)wsb;     // x bf16 padded swizzled (71.4MB)
    unsigned short* y3b = (unsigned short*)wsb;     // y3 bf16 NCHW (67MB) — io dead by then
    unsigned short* Wt1 = (unsigned short*)(wsb + (size_t)71368704);   // 294,912 B
    unsigned short* Wt2 = Wt1 + 147456;                                // 294,912 B
    float* part = (float*)(wsb + (size_t)71368704 + 589824);           // 2 MB
    float* st1  = part + 2048 * 256;
    float* st2  = st1 + 256;
    float* msA  = st2 + 256;                                           // 64*128
    float* mhA  = msA + 64 * 128;                                      // 64*128
    float* qsum = mhA + 64 * 128;                                      // 512*64

    prep_w_k<<<1152, 256, 0, stream>>>(w1, w2, Wt1, Wt2);
    // x -> padded swizzled bf16 (interior) + border zeroing (tail blocks)
    to_nhwc_k<<<17424, 256, 0, stream>>>(x, io);
    // conv1: io (ws) -> y1 (d_out) + BN1 partials
    conv_mfma_k<1><<<2048, 256, 0, stream>>>(io, Wt1, nullptr, nullptr, y1, part);
    bn_finalize_k<<<128, 256, 0, stream>>>(part, g1, b1, st1);
    // per-(n,c) activation means -> combined mask*scale/shift
    maskpart_k<<<512, 256, 0, stream>>>(y1, st1, qsum);
    maskfin_k<<<64, 128, 0, stream>>>(qsum, st1, msA, mhA);
    // conv2: y1 (BN1+relu+mask in staging) -> y3 bf16 (ws) + BN2 partials
    conv_mfma_k<2><<<2048, 256, 0, stream>>>(y1, Wt2, msA, mhA, y3b, part);
    bn_finalize_k<<<128, 256, 0, stream>>>(part, g2, b2, st2);
    // final: relu(bn2(y3)+x) -> d_out (y1 dead)
    final_k<<<8192, 256, 0, stream>>>(y3b, x, st2, out);
}

// Round 21
// 310.273 us; speedup vs baseline: 1.0536x; 1.0536x over previous
//
#include <hip/hip_runtime.h>

typedef short short8 __attribute__((ext_vector_type(8)));
typedef short short4v __attribute__((ext_vector_type(4)));
typedef float f32x4 __attribute__((ext_vector_type(4)));
typedef unsigned int u32;

#define EPSF 1e-5f
#define THRF 0.2987f

constexpr int N_ = 64, C_ = 128;
constexpr int PLANE = 4096;
constexpr size_t TENSOR = (size_t)N_ * C_ * PLANE;  // 33554432
constexpr int NHW = N_ * PLANE;                     // 262144
constexpr int PUNITS = 66 * 66 * 8;                 // 34848 16B-units per (half,n) plane

__device__ __forceinline__ unsigned short f2bf(float f) {
    unsigned u = __float_as_uint(f);
    u += 0x7fffu + ((u >> 16) & 1u);  // RNE
    return (unsigned short)(u >> 16);
}
__device__ __forceinline__ float bf2f(unsigned short h) {
    return __uint_as_float((unsigned)h << 16);
}
__device__ __forceinline__ void gld16(const unsigned short* g, unsigned short* l) {
    __builtin_amdgcn_global_load_lds(
        (const __attribute__((address_space(1))) u32*)g,
        (__attribute__((address_space(3))) u32*)l, 16, 0, 0);
}

// ---------- weight prep: [co][ci][3][3] fp32 -> [36 steps][128 co][32 ci] bf16
__global__ __launch_bounds__(256) void prep_w_k(const float* __restrict__ w1,
                                                const float* __restrict__ w2,
                                                unsigned short* __restrict__ Wt1,
                                                unsigned short* __restrict__ Wt2) {
    int idx = blockIdx.x * 256 + threadIdx.x;  // 0..294911
    const int sel = idx >= 147456;
    const float* src = sel ? w2 : w1;
    unsigned short* dst = sel ? Wt2 : Wt1;
    const int r = idx - sel * 147456;
    const int tap = r >> 14;
    const int rem = r & 16383;
    const int co = rem >> 7, ci = rem & 127;
    const int half = ci >> 6, csh = (ci >> 5) & 1;
    const int s = half * 18 + tap * 2 + csh;
    dst[(size_t)s * 4096 + co * 32 + (ci & 31)] = f2bf(src[(co * 128 + ci) * 9 + tap]);
}

// ---------- zero the padded borders of io only ----------
__global__ __launch_bounds__(256) void zero_border_k(unsigned short* __restrict__ io) {
    int idx = blockIdx.x * 256 + threadIdx.x;  // 128*2080 = 266240
    if (idx >= 266240) return;
    const int plane = idx / 2080;
    const int t = idx - plane * 2080;
    int sp;
    if (t < 528) sp = t >> 3;
    else if (t < 1056) sp = 65 * 66 + ((t - 528) >> 3);
    else if (t < 1568) sp = (((t - 1056) >> 3) + 1) * 66;
    else sp = (((t - 1568) >> 3) + 1) * 66 + 65;
    const size_t off = ((size_t)plane * PUNITS + sp * 8 + (t & 7)) * 8;
    *(short8*)&io[off] = (short8){0, 0, 0, 0, 0, 0, 0, 0};
}

// ---------- NCHW fp32 -> padded swizzled NHWC bf16 (x only) ----------
__global__ __launch_bounds__(256) void to_nhwc_k(const float* __restrict__ src,
                                                 unsigned short* __restrict__ dst) {
    __shared__ __align__(16) unsigned short tl[64 * 40];
    const int b = blockIdx.x;
    const int c0 = (b & 3) * 32;
    const int h  = (b >> 2) & 63;
    const int n  = b >> 8;
    const int t  = threadIdx.x;
    for (int i = t; i < 512; i += 256) {
        const int cl = i >> 4;
        const int c  = c0 + cl;
        const int w4 = (i & 15) * 4;
        float4 v = *(const float4*)&src[(size_t)(n * 128 + c) * 4096 + h * 64 + w4];
        tl[(w4 + 0) * 40 + cl] = f2bf(v.x);
        tl[(w4 + 1) * 40 + cl] = f2bf(v.y);
        tl[(w4 + 2) * 40 + cl] = f2bf(v.z);
        tl[(w4 + 3) * 40 + cl] = f2bf(v.w);
    }
    __syncthreads();
    const int w = t >> 2, cs = t & 3;
    short8 v = *(const short8*)&tl[w * 40 + cs * 8];
    const int c = c0 + cs * 8;
    const int half = c >> 6, cig = (c >> 3) & 7;
    const int colp = w + 1, rowp = h + 1;
    const size_t off = ((size_t)(half * 64 + n) * PUNITS
                        + (size_t)(rowp * 66 + colp) * 8 + (cig ^ (colp & 7))) * 8;
    *(short8*)&dst[off] = v;
}

// ---------- conv3x3 MFMA implicit GEMM (R17/R19 core, verified 115us) ----------
template <int STAGE>
__global__ __launch_bounds__(256, 3) void conv_mfma_k(
    const unsigned short* __restrict__ inT, const unsigned short* __restrict__ Wt,
    const float* __restrict__ msA, const float* __restrict__ mhA,
    unsigned short* __restrict__ outB, float* __restrict__ part) {
    __shared__ __align__(16) unsigned short sIn[2112 * 8];  // 33,792 B
    __shared__ float fS[256], fQ[256];                      // 2,048 B

    // XCD-chunked bijective swizzle (2048 % 8 == 0)
    const int b  = (blockIdx.x & 7) * 256 + (blockIdx.x >> 3);
    const int h0 = (b & 31) * 2;
    const int n  = b >> 5;
    const int tid  = threadIdx.x;
    const int lane = tid & 63;
    const int wid  = tid >> 6;
    const int co_base = (wid >> 1) * 64;
    const int px_base = (wid & 1) * 64;
    const int lr = lane & 15;
    const int lg = lane >> 4;

    f32x4 acc[4][4];
#pragma unroll
    for (int i = 0; i < 4; ++i)
#pragma unroll
        for (int j = 0; j < 4; ++j) acc[i][j] = (f32x4){0.f, 0.f, 0.f, 0.f};

    const int nc = n * 128;
    const unsigned short* wlane = Wt + (size_t)(co_base + lr) * 32 + lg * 8;

    // Precomputed per-lane LDS byte addresses
    int ldsQ[4][2][3];
#pragma unroll
    for (int j = 0; j < 4; ++j) {
        const int px = px_base + j * 16 + lr;
        const int r = px >> 6, c = px & 63;
#pragma unroll
        for (int csh = 0; csh < 2; ++csh)
#pragma unroll
            for (int dc = 0; dc < 3; ++dc) {
                const int cig = csh * 4 + lg;
                ldsQ[j][csh][dc] = (r * 66 + c + dc) * 128 + (cig ^ ((c + dc) & 7)) * 16;
            }
    }

    auto stage_in = [&](int half) {
        const unsigned short* src =
            inT + ((size_t)(half * 64 + n) * PUNITS + (size_t)h0 * 66 * 8) * 8;
        if (STAGE == 1) {
            for (int c = wid; c < 33; c += 4)
                gld16(src + (c * 64 + lane) * 8, &sIn[c * 512]);
        } else {
            const int ncb = nc + half * 64;
            for (int i = tid; i < 2112; i += 256) {
                const int sp = i >> 3, ul = i & 7;
                const int rq = sp / 66;
                const int colp = sp - rq * 66;
                const int rp = h0 + rq;
                short8 v = {0, 0, 0, 0, 0, 0, 0, 0};
                if (rp != 0 && rp != 65 && colp != 0 && colp != 65) {
                    v = *(const short8*)&src[i * 8];
                    const int cig = ul ^ (colp & 7);
                    const int cb = ncb + cig * 8;
                    const float4 m0 = *(const float4*)&msA[cb];
                    const float4 m1 = *(const float4*)&msA[cb + 4];
                    const float4 a0 = *(const float4*)&mhA[cb];
                    const float4 a1 = *(const float4*)&mhA[cb + 4];
                    short8 w;
                    w[0] = (short)f2bf(fmaxf(fmaf(bf2f((unsigned short)v[0]), m0.x, a0.x), 0.f));
                    w[1] = (short)f2bf(fmaxf(fmaf(bf2f((unsigned short)v[1]), m0.y, a0.y), 0.f));
                    w[2] = (short)f2bf(fmaxf(fmaf(bf2f((unsigned short)v[2]), m0.z, a0.z), 0.f));
                    w[3] = (short)f2bf(fmaxf(fmaf(bf2f((unsigned short)v[3]), m0.w, a0.w), 0.f));
                    w[4] = (short)f2bf(fmaxf(fmaf(bf2f((unsigned short)v[4]), m1.x, a1.x), 0.f));
                    w[5] = (short)f2bf(fmaxf(fmaf(bf2f((unsigned short)v[5]), m1.y, a1.y), 0.f));
                    w[6] = (short)f2bf(fmaxf(fmaf(bf2f((unsigned short)v[6]), m1.z, a1.z), 0.f));
                    w[7] = (short)f2bf(fmaxf(fmaf(bf2f((unsigned short)v[7]), m1.w, a1.w), 0.f));
                    v = w;
                }
                *(short8*)&sIn[i * 8] = v;
            }
        }
    };

    auto ldw2 = [&](short8* dst, const unsigned short* p) {
#pragma unroll
        for (int i = 0; i < 4; ++i)
            dst[i] = *(const short8*)&p[i * 512];
    };
    auto ldb = [&](short8* bfv, int dr, int dc, int csh) {
#pragma unroll
        for (int j = 0; j < 4; ++j)
            bfv[j] = *(const short8*)((const char*)sIn + ldsQ[j][csh][dc] + dr * 8448);
    };
    auto mm = [&](short8* af, short8* bfv) {
        __builtin_amdgcn_s_setprio(1);
#pragma unroll
        for (int i = 0; i < 4; ++i)
#pragma unroll
            for (int j = 0; j < 4; ++j)
                acc[i][j] = __builtin_amdgcn_mfma_f32_16x16x32_bf16(af[i], bfv[j],
                                                                    acc[i][j], 0, 0, 0);
        __builtin_amdgcn_s_setprio(0);
    };

    short8 afA[4], afB[4], bfv[4];
    const unsigned short* wpA = wlane;         // even slices
    const unsigned short* wpB = wlane + 4096;  // odd slices

    // ---- prologue
    stage_in(0);
    ldw2(afA, wpA);
    ldw2(afB, wpB);
    __syncthreads();

#pragma unroll
    for (int half = 0; half < 2; ++half) {
#pragma unroll
        for (int it = 0; it < 9; ++it) {
            const int dr = it / 3, dc = it - dr * 3;
            ldb(bfv, dr, dc, 0);
            mm(afA, bfv);
            if (it < 8) { wpA += 8192; ldw2(afA, wpA); }
            ldb(bfv, dr, dc, 1);
            mm(afB, bfv);
            if (it < 8) { wpB += 8192; ldw2(afB, wpB); }
        }
        if (half == 0) {
            wpA += 8192; ldw2(afA, wpA);  // slice 18
            wpB += 8192; ldw2(afB, wpB);  // slice 19
            __syncthreads();  // all waves done reading sIn half0
            stage_in(1);
            __syncthreads();  // sIn half1 visible
        }
    }

    // ---- BN partials
#pragma unroll
    for (int i = 0; i < 4; ++i)
#pragma unroll
        for (int q = 0; q < 4; ++q) {
            float v = acc[i][0][q] + acc[i][1][q] + acc[i][2][q] + acc[i][3][q];
            float w = acc[i][0][q] * acc[i][0][q] + acc[i][1][q] * acc[i][1][q]
                    + acc[i][2][q] * acc[i][2][q] + acc[i][3][q] * acc[i][3][q];
#pragma unroll
            for (int m = 1; m < 16; m <<= 1) {
                v += __shfl_xor(v, m);
                w += __shfl_xor(w, m);
            }
            if (lr == 0) {
                const int colocal = i * 16 + lg * 4 + q;
                fS[wid * 64 + colocal] = v;
                fQ[wid * 64 + colocal] = w;
            }
        }
    __syncthreads();
    if (tid < 128) {
        const int grp = tid >> 6, cl = tid & 63;
        part[(size_t)b * 256 + tid]       = fS[(grp * 2) * 64 + cl] + fS[(grp * 2 + 1) * 64 + cl];
        part[(size_t)b * 256 + 128 + tid] = fQ[(grp * 2) * 64 + cl] + fQ[(grp * 2 + 1) * 64 + cl];
    }

    // ---- write output
    if (STAGE == 1) {
        const int h = h0 + (px_base >> 6);
        const int rowp = h + 1;
        const size_t plane = (size_t)((co_base >> 6) * 64 + n) * PUNITS * 8;
        const int pg = lg >> 1;
#pragma unroll
        for (int j = 0; j < 4; ++j) {
            const int w = j * 16 + lr;
            const int colp = w + 1;
            const size_t spoff = plane + (size_t)(rowp * 66 + colp) * 8 * 8;
#pragma unroll
            for (int i = 0; i < 4; ++i) {
                u32 p0 = ((u32)f2bf(acc[i][j][1]) << 16) | f2bf(acc[i][j][0]);
                u32 p1 = ((u32)f2bf(acc[i][j][3]) << 16) | f2bf(acc[i][j][2]);
                const u32 q0 = __shfl_xor(p0, 16);
                const u32 q1 = __shfl_xor(p1, 16);
                if ((lg & 1) == 0) {
                    const int cig = (i * 2 + pg) & 7;
                    u32 st4[4] = {p0, p1, q0, q1};
                    *(short8*)&outB[spoff + (size_t)(cig ^ (colp & 7)) * 8] =
                        *(const short8*)st4;
                }
            }
        }
    } else {
        const size_t outN = (size_t)n * 128 * 4096;
#pragma unroll
        for (int i = 0; i < 4; ++i) {
            const int cob = co_base + i * 16 + lg * 4;
#pragma unroll
            for (int q = 0; q < 4; ++q) {
                unsigned short* op = outB + outN + (size_t)(cob + q) * 4096
                                     + h0 * 64 + px_base + lr;
#pragma unroll
                for (int j = 0; j < 4; ++j) op[j * 16] = f2bf(acc[i][j][q]);
            }
        }
    }
}

// ---------- fold per-block partials -> per-channel scale/shift ----------
__global__ __launch_bounds__(256) void bn_finalize_k(const float* __restrict__ part,
                                                     const float* __restrict__ gamma,
                                                     const float* __restrict__ beta,
                                                     float* __restrict__ st) {
    const int c = blockIdx.x;
    float s = 0.f, q = 0.f;
    for (int b = threadIdx.x; b < 2048; b += 256) {
        s += part[(size_t)b * 256 + c];
        q += part[(size_t)b * 256 + 128 + c];
    }
    __shared__ float rs[256], rq[256];
    rs[threadIdx.x] = s; rq[threadIdx.x] = q;
    __syncthreads();
    for (int o = 128; o > 0; o >>= 1) {
        if (threadIdx.x < o) {
            rs[threadIdx.x] += rs[threadIdx.x + o];
            rq[threadIdx.x] += rq[threadIdx.x + o];
        }
        __syncthreads();
    }
    if (threadIdx.x == 0) {
        const float inv  = 1.f / (float)NHW;
        const float mean = rs[0] * inv;
        const float var  = rq[0] * inv - mean * mean;
        const float sc   = gamma[c] * rsqrtf(var + EPSF);
        st[c]       = sc;
        st[C_ + c]  = fmaf(-mean, sc, beta[c]);
    }
}

// ---------- per-(n,half,row-quarter) partial sums of relu(bn1(y1)) ----------
__global__ __launch_bounds__(256) void maskpart_k(const unsigned short* __restrict__ y1,
                                                  const float* __restrict__ st,
                                                  float* __restrict__ qsum) {
    const int blk = blockIdx.x;
    const int n = blk >> 3, half = (blk >> 2) & 1, rq = blk & 3;
    const int t = threadIdx.x;
    const int colg = t & 63;
    const int p = t >> 6;
    const int colp = 1 + colg;
    float scv[2][8], shv[2][8], a[2][8];
#pragma unroll
    for (int k = 0; k < 2; ++k)
#pragma unroll
        for (int e = 0; e < 8; ++e) {
            const int c = half * 64 + (2 * p + k) * 8 + e;
            scv[k][e] = st[c];
            shv[k][e] = st[128 + c];
            a[k][e] = 0.f;
        }
    const size_t plane = (size_t)(half * 64 + n) * PUNITS * 8;
    for (int rowp = rq * 16 + 1; rowp <= rq * 16 + 16; ++rowp) {
        const int sp = rowp * 66 + colp;
#pragma unroll
        for (int k = 0; k < 2; ++k) {
            const int cig = 2 * p + k;
            short8 v = *(const short8*)&y1[plane + ((size_t)sp * 8 + (cig ^ (colp & 7))) * 8];
#pragma unroll
            for (int e = 0; e < 8; ++e)
                a[k][e] += fmaxf(fmaf(bf2f((unsigned short)v[e]), scv[k][e], shv[k][e]), 0.f);
        }
    }
    __shared__ float lds[256][16];
#pragma unroll
    for (int k = 0; k < 2; ++k)
#pragma unroll
        for (int e = 0; e < 8; ++e) lds[t][k * 8 + e] = a[k][e];
    __syncthreads();
    if (t < 64) {
        const int cig = t >> 3, e = t & 7, p2 = cig >> 1, k2 = cig & 1;
        float s = 0.f;
        for (int cg = 0; cg < 64; ++cg) s += lds[p2 * 64 + cg][k2 * 8 + e];
        qsum[(size_t)blk * 64 + t] = s;
    }
}

// ---------- finalize mask -> combined ms/mh per (n,c) ----------
__global__ void maskfin_k(const float* __restrict__ qsum, const float* __restrict__ st,
                          float* __restrict__ msA, float* __restrict__ mhA) {
    const int n = blockIdx.x, c = threadIdx.x;
    if (c >= 128) return;
    const int half = c >> 6, cl = c & 63;
    float s = 0.f;
#pragma unroll
    for (int rq = 0; rq < 4; ++rq)
        s += qsum[(size_t)(n * 8 + half * 4 + rq) * 64 + cl];
    const float m = (s * (1.f / 4096.f) >= THRF) ? 1.f : 0.f;
    msA[n * 128 + c] = st[c] * m;
    mhA[n * 128 + c] = st[128 + c] * m;
}

// ---------- final: relu(bn2(y3 bf16) + x), NCHW fp32 out ----------
__global__ __launch_bounds__(256) void final_k(const unsigned short* __restrict__ y3,
                                               const float* __restrict__ x,
                                               const float* __restrict__ st,
                                               float* __restrict__ out) {
    const size_t total8 = TENSOR / 8;
    for (size_t g = (size_t)blockIdx.x * 256 + threadIdx.x; g < total8;
         g += (size_t)gridDim.x * 256) {
        const int c = (int)((g >> 9) & (C_ - 1));
        const float sc = st[c], sh = st[C_ + c];
        short8 yv = *(const short8*)&y3[g * 8];
        float4 a0 = ((const float4*)x)[g * 2];
        float4 a1 = ((const float4*)x)[g * 2 + 1];
        float4 o0, o1;
        o0.x = fmaxf(fmaf(bf2f((unsigned short)yv[0]), sc, sh) + a0.x, 0.f);
        o0.y = fmaxf(fmaf(bf2f((unsigned short)yv[1]), sc, sh) + a0.y, 0.f);
        o0.z = fmaxf(fmaf(bf2f((unsigned short)yv[2]), sc, sh) + a0.z, 0.f);
        o0.w = fmaxf(fmaf(bf2f((unsigned short)yv[3]), sc, sh) + a0.w, 0.f);
        o1.x = fmaxf(fmaf(bf2f((unsigned short)yv[4]), sc, sh) + a1.x, 0.f);
        o1.y = fmaxf(fmaf(bf2f((unsigned short)yv[5]), sc, sh) + a1.y, 0.f);
        o1.z = fmaxf(fmaf(bf2f((unsigned short)yv[6]), sc, sh) + a1.z, 0.f);
        o1.w = fmaxf(fmaf(bf2f((unsigned short)yv[7]), sc, sh) + a1.w, 0.f);
        ((float4*)out)[g * 2]     = o0;
        ((float4*)out)[g * 2 + 1] = o1;
    }
}

extern "C" void kernel_launch(void* const* d_in, const int* in_sizes, int n_in,
                              void* d_out, int out_size, void* d_ws, size_t ws_size,
                              hipStream_t stream) {
    const float* x  = (const float*)d_in[0];
    const float* w1 = (const float*)d_in[1];
    const float* g1 = (const float*)d_in[2];
    const float* b1 = (const float*)d_in[3];
    const float* w2 = (const float*)d_in[4];
    const float* g2 = (const float*)d_in[5];
    const float* b2 = (const float*)d_in[6];
    float* out = (float*)d_out;

    // y1 (padded swizzled bf16, 71.4MB) lives in d_out; final overwrites it.
    unsigned short* y1 = (unsigned short*)d_out;

    char* wsb = (char*)d_ws;
    unsigned short* io  = (unsigned short*)wsb;     // x bf16 padded swizzled (71.4MB)
    unsigned short* y3b = (unsigned short*)wsb;     // y3 bf16 NCHW (67MB) — io dead by then
    unsigned short* Wt1 = (unsigned short*)(wsb + (size_t)71368704);   // 294,912 B
    unsigned short* Wt2 = Wt1 + 147456;                                // 294,912 B
    float* part = (float*)(wsb + (size_t)71368704 + 589824);           // 2 MB
    float* st1  = part + 2048 * 256;
    float* st2  = st1 + 256;
    float* msA  = st2 + 256;                                           // 64*128
    float* mhA  = msA + 64 * 128;                                      // 64*128
    float* qsum = mhA + 64 * 128;                                      // 512*64

    prep_w_k<<<1152, 256, 0, stream>>>(w1, w2, Wt1, Wt2);
    zero_border_k<<<1040, 256, 0, stream>>>(io);
    to_nhwc_k<<<16384, 256, 0, stream>>>(x, io);
    // conv1: io (ws) -> y1 (d_out) + BN1 partials
    conv_mfma_k<1><<<2048, 256, 0, stream>>>(io, Wt1, nullptr, nullptr, y1, part);
    bn_finalize_k<<<128, 256, 0, stream>>>(part, g1, b1, st1);
    // per-(n,c) activation means -> combined mask*scale/shift
    maskpart_k<<<512, 256, 0, stream>>>(y1, st1, qsum);
    maskfin_k<<<64, 128, 0, stream>>>(qsum, st1, msA, mhA);
    // conv2: y1 (BN1+relu+mask in staging) -> y3 bf16 (ws) + BN2 partials
    conv_mfma_k<2><<<2048, 256, 0, stream>>>(y1, Wt2, msA, mhA, y3b, part);
    bn_finalize_k<<<128, 256, 0, stream>>>(part, g2, b2, st2);
    // final: relu(bn2(y3)+x) -> d_out (y1 dead)
    final_k<<<8192, 256, 0, stream>>>(y3b, x, st2, out);
}